// Round 1
// baseline (97.480 us; speedup 1.0000x reference)
//
#include <hip/hip_runtime.h>
#include <math.h>
#include <limits.h>

#define SS 8
#define CC 16
#define HH 64
#define WW 96
#define DD 64
#define NN (HH*WW)
#define PW 100            // padded width: 2 zero cols each side
#define PH 66             // padded height: 1 zero row each side
#define PN (PH*PW)        // 6600 padded pixels per source

#define BOX_W 32          // staged box capacity: cols (incl. +1 tap col)
#define BOX_H 24          // staged box capacity: rows
#define ROWP 65           // LDS row pitch in H8 units (64 data + 1 pad -> bank spread)

typedef _Float16 h2 __attribute__((ext_vector_type(2)));
struct alignas(16) H8 { h2 v[4]; };   // 8 halfs = 16 B

typedef const __attribute__((address_space(1))) unsigned int gu32;
typedef __attribute__((address_space(3))) unsigned int lu32;

// Prep: transpose+convert src (S,C,H,W) -> f16 zero-padded channel-last
// (S, PH, PW, C); cur (C,H,W) -> f16 (H,W,C). Border texels written as zeros
// so OOB bilinear taps read 0 with no per-tap masking in the main kernel.
// Also folded projection matrices and the 64 log-spaced depths.
__global__ __launch_bounds__(256) void prep_kernel(
    const float* __restrict__ cur, const float* __restrict__ src,
    const float* __restrict__ ext, const float* __restrict__ Ks,
    const float* __restrict__ invK, const float* __restrict__ mnp,
    const float* __restrict__ mxp,
    _Float16* __restrict__ srcT, _Float16* __restrict__ curT,
    float* __restrict__ mats, float* __restrict__ depths)
{
    int tid = blockIdx.x * 256 + threadIdx.x;
    const int srcPad = SS * PN;             // 52800
    if (tid < srcPad) {
        int s = tid / PN;
        int rem = tid % PN;
        int py = rem / PW;
        int px = rem % PW;
        _Float16 v[CC] = {};                // zeros for border texels
        if (py >= 1 && py <= HH && px >= 2 && px <= WW + 1) {
            int p = (py - 1) * WW + (px - 2);
            const float* base = src + (size_t)s * CC * NN + p;
#pragma unroll
            for (int c = 0; c < CC; ++c) v[c] = (_Float16)base[c * NN];
        }
        H8* o = (H8*)(srcT + (size_t)tid * CC);
        o[0] = *(H8*)&v[0];
        o[1] = *(H8*)&v[8];
    } else if (tid < srcPad + NN) {
        int p = tid - srcPad;
        const float* base = cur + p;
        _Float16 v[CC];
#pragma unroll
        for (int c = 0; c < CC; ++c) v[c] = (_Float16)base[c * NN];
        H8* o = (H8*)(curT + (size_t)p * CC);
        o[0] = *(H8*)&v[0];
        o[1] = *(H8*)&v[8];
    }
    if (blockIdx.x == 0) {
        if (threadIdx.x < DD) {
            float lmn = logf(mnp[0]);
            float lr  = logf(mxp[0] / mnp[0]);
            depths[threadIdx.x] = expf(lmn + lr * ((float)threadIdx.x * (1.0f / (DD - 1))));
        } else if (threadIdx.x < DD + SS) {
            int s = threadIdx.x - DD;
            float P[3][4];
            for (int i = 0; i < 3; ++i)
                for (int j = 0; j < 4; ++j) {
                    float a = 0.f;
                    for (int k = 0; k < 4; ++k)
                        a += Ks[s * 16 + i * 4 + k] * ext[s * 16 + k * 4 + j];
                    P[i][j] = a;
                }
            for (int i = 0; i < 3; ++i) {
                for (int j = 0; j < 3; ++j) {
                    float a = 0.f;
                    for (int k = 0; k < 3; ++k)
                        a += P[i][k] * invK[k * 4 + j];
                    mats[s * 12 + i * 3 + j] = a;
                }
                mats[s * 12 + 9 + i] = P[i][3];
            }
        }
    }
}

// 2x2-tap bilinear dot of 16-ch f16 features vs cur features.
// r0/r1 point at the LEFT tap of row0/row1; taps are contiguous (4x H8 per row).
__device__ __forceinline__ float bil_dot(const H8* r0, const H8* r1,
                                         const H8& cA, const H8& cB,
                                         float wx, float wy)
{
    H8 a0 = r0[0], a1 = r0[1], a2 = r0[2], a3 = r0[3];
    H8 b0 = r1[0], b1 = r1[1], b2 = r1[2], b3 = r1[3];
    float dL0 = 0.f, dR0 = 0.f, dL1 = 0.f, dR1 = 0.f;
#pragma unroll
    for (int q = 0; q < 4; ++q) {
        dL0 = __builtin_amdgcn_fdot2(a0.v[q], cA.v[q], dL0, false);
        dL0 = __builtin_amdgcn_fdot2(a1.v[q], cB.v[q], dL0, false);
        dR0 = __builtin_amdgcn_fdot2(a2.v[q], cA.v[q], dR0, false);
        dR0 = __builtin_amdgcn_fdot2(a3.v[q], cB.v[q], dR0, false);
        dL1 = __builtin_amdgcn_fdot2(b0.v[q], cA.v[q], dL1, false);
        dL1 = __builtin_amdgcn_fdot2(b1.v[q], cB.v[q], dL1, false);
        dR1 = __builtin_amdgcn_fdot2(b2.v[q], cA.v[q], dR1, false);
        dR1 = __builtin_amdgcn_fdot2(b3.v[q], cB.v[q], dR1, false);
    }
    float d0 = dL0 + wx * (dR0 - dL0);
    float d1 = dL1 + wx * (dR1 - dL1);
    return d0 + wy * (d1 - d0);
}

// Main: block = 8x8 pixel tile x 4 consecutive depths (one depth per wave).
// Per source: block-reduce the tap bounding box, async-stage the box into LDS
// with coalesced global_load_lds (16 B/lane), then bilinear dots from LDS.
// Uniform fallback to direct global gathers if the box exceeds capacity.
__global__ __launch_bounds__(256, 6) void cost_kernel(
    const _Float16* __restrict__ curT, const _Float16* __restrict__ srcT,
    const float* __restrict__ mats, const float* __restrict__ depths,
    float* __restrict__ out)
{
    __shared__ H8 stage[BOX_H * ROWP];   // 24.4 KB -> 6 blocks/CU
    __shared__ int red[8];               // double-buffered {xmin,xmax,ymin,ymax}

    int tid = threadIdx.x;
    const int TX = WW / 8;                 // 12
    const int TY = HH / 8;                 // 8
    int bx = blockIdx.x;
    int dg  = bx / (TX * TY);              // 0..15
    int rem = bx % (TX * TY);
    int tyi = rem / TX;
    int txi = rem % TX;
    int lane = tid & 63;
    int dsub = tid >> 6;                   // wave index = depth sub-index
    int d  = dg * 4 + dsub;
    int px = txi * 8 + (lane & 7);
    int py = tyi * 8 + (lane >> 3);
    int n  = py * WW + px;

    float x = (float)px + 0.5f;
    float y = (float)py + 0.5f;

    const H8* cp = (const H8*)(curT + (size_t)n * CC);
    H8 cA = cp[0], cB = cp[1];
    // d is wave-uniform; force scalar load of the depth
    float depth = depths[__builtin_amdgcn_readfirstlane(d)];

    float acc = 0.f;
#pragma unroll 1
    for (int s = 0; s < SS; ++s) {
        const float* m = &mats[s * 12];    // s loop-uniform -> s_load
        float m0 = m[0], m1 = m[1], m2 = m[2], m3 = m[3], m4 = m[4], m5 = m[5];
        float m6 = m[6], m7 = m[7], m8 = m[8], m9 = m[9], m10 = m[10], m11 = m[11];
        float qx = m0 * x + m1 * y + m2;
        float qy = m3 * x + m4 * y + m5;
        float qz = m6 * x + m7 * y + m8;
        float pz = depth * qz + m11;
        bool ok = pz > 0.f;
        float r = __builtin_amdgcn_rcpf(pz + 1e-8f);   // u = px/(z+EPS) per ref
        float u = (depth * qx + m9)  * r - 0.5f;
        float v = (depth * qy + m10) * r - 0.5f;
        bool contrib = ok && (u > -1.f) && (u < (float)WW) && (v > -1.f) && (v < (float)HH);
        // float-side clamps keep both taps of each pair inside the padded image
        float uc = ok ? fminf(fmaxf(u, -2.0f), 96.5f) : -2.0f;
        float vc = ok ? fminf(fmaxf(v, -1.0f), 64.5f) : -1.0f;
        float x0f = floorf(uc), y0f = floorf(vc);
        float wx = uc - x0f, wy = vc - y0f;
        int x0p = (int)x0f + 2;                  // [0, 98]
        int y0p = (int)y0f + 1;                  // [0, 65]
        int y1p = min(y0p + 1, PH - 1);          // [1, 65]

        // ---- block-wide tap bounding box over contributing lanes ----
        int* base = &red[(s & 1) * 4];           // double-buffer: no init/read race
        int cx0 = contrib ? x0p : INT_MAX;
        int cx1 = contrib ? x0p : INT_MIN;
        int cy0 = contrib ? y0p : INT_MAX;
        int cy1 = contrib ? y1p : INT_MIN;
        if (tid < 4) base[tid] = (tid & 1) ? INT_MIN : INT_MAX;
        __syncthreads();                          // init visible; prev-s LDS reads done
#pragma unroll
        for (int o = 32; o; o >>= 1) {
            cx0 = min(cx0, __shfl_xor(cx0, o));
            cx1 = max(cx1, __shfl_xor(cx1, o));
            cy0 = min(cy0, __shfl_xor(cy0, o));
            cy1 = max(cy1, __shfl_xor(cy1, o));
        }
        if (lane == 0) {
            atomicMin(&base[0], cx0);
            atomicMax(&base[1], cx1);
            atomicMin(&base[2], cy0);
            atomicMax(&base[3], cy1);
        }
        __syncthreads();
        int xlo = base[0], xhi = base[1], ylo = base[2], yhi = base[3];
        if (xhi == INT_MIN) continue;            // nobody contributes: exact 0
        int bw = xhi + 2 - xlo;                  // cols xlo .. xhi+1
        int bh = yhi + 1 - ylo;                  // rows ylo .. yhi  (yhi = max y1p)
        const _Float16* sb = srcT + (size_t)s * (PN * CC);

        if (bw <= BOX_W && bh <= BOX_H) {
            // Stage: each wave takes rows dsub, dsub+4, ...; one full-wave
            // global_load_lds per row = 32 px x 32 B, coalesced, direct to LDS.
            // (Reads up to 32 px wide regardless of bw; overshoot stays inside
            // the workspace and lands in unread LDS slots.)
            for (int rr = dsub; rr < bh; rr += 4) {
                const _Float16* grow = sb + ((size_t)(ylo + rr) * PW + xlo) * CC;
                __builtin_amdgcn_global_load_lds((gu32*)(grow + (size_t)lane * 8),
                                                 (lu32*)&stage[rr * ROWP], 16, 0, 0);
            }
            __syncthreads();                      // vmcnt(0) drain + barrier
            if (contrib) {
                int lx = x0p - xlo;               // 0 .. bw-2 <= 30
                const H8* l0 = &stage[(y0p - ylo) * ROWP + lx * 2];
                const H8* l1 = &stage[(y1p - ylo) * ROWP + lx * 2];
                acc += bil_dot(l0, l1, cA, cB, wx, wy);
            }
        } else {
            // safety fallback: direct global gathers (original path)
            if (contrib) {
                const H8* r0 = (const H8*)(sb + (size_t)(y0p * PW + x0p) * CC);
                const H8* r1 = (const H8*)(sb + (size_t)(y1p * PW + x0p) * CC);
                acc += bil_dot(r0, r1, cA, cB, wx, wy);
            }
        }
    }
    out[(size_t)d * NN + n] = acc;                      // cost_volume
    out[(size_t)DD * NN + (size_t)d * NN + n] = depth;  // depth_planes
}

extern "C" void kernel_launch(void* const* d_in, const int* in_sizes, int n_in,
                              void* d_out, int out_size, void* d_ws, size_t ws_size,
                              hipStream_t stream) {
    const float* cur  = (const float*)d_in[0];
    const float* src  = (const float*)d_in[1];
    const float* ext  = (const float*)d_in[2];
    const float* Ks   = (const float*)d_in[3];
    const float* invK = (const float*)d_in[4];
    const float* mn   = (const float*)d_in[5];
    const float* mx   = (const float*)d_in[6];
    float* out = (float*)d_out;

    char* ws = (char*)d_ws;
    _Float16* srcT = (_Float16*)ws;                     // S*PN*C halfs ≈ 1.69 MB
    _Float16* curT = srcT + (size_t)SS * PN * CC;       // N*C halfs
    float* mats    = (float*)(curT + (size_t)NN * CC);  // 96
    float* depths  = mats + SS * 12;                    // 64

    int prepThreads = SS * PN + NN;                     // 58944
    int prepBlocks = (prepThreads + 255) / 256;         // 231
    prep_kernel<<<prepBlocks, 256, 0, stream>>>(cur, src, ext, Ks, invK, mn, mx,
                                                srcT, curT, mats, depths);
    cost_kernel<<<(DD / 4) * (WW / 8) * (HH / 8), 256, 0, stream>>>(curT, srcT, mats, depths, out);
}

// Round 3
// 91.526 us; speedup vs baseline: 1.0651x; 1.0651x over previous
//
#include <hip/hip_runtime.h>
#include <math.h>

#define SS 8
#define CC 16
#define HH 64
#define WW 96
#define DD 64
#define NN (HH*WW)
#define PW 100            // padded width: 2 zero cols each side
#define PH 66             // padded height: 1 zero row each side
#define PN (PH*PW)        // 6600 padded pixels per source

typedef _Float16 h2 __attribute__((ext_vector_type(2)));
struct alignas(16) H8 { h2 v[4]; };   // 8 halfs = 16 B

// Prep: transpose+convert src (S,C,H,W) -> f16 zero-padded channel-last
// (S, PH, PW, C); cur (C,H,W) -> f16 (H,W,C). Border texels written as zeros
// so OOB bilinear taps read 0 with no per-tap masking in the main kernel.
// Also folded projection matrices and the 64 log-spaced depths.
__global__ __launch_bounds__(256) void prep_kernel(
    const float* __restrict__ cur, const float* __restrict__ src,
    const float* __restrict__ ext, const float* __restrict__ Ks,
    const float* __restrict__ invK, const float* __restrict__ mnp,
    const float* __restrict__ mxp,
    _Float16* __restrict__ srcT, _Float16* __restrict__ curT,
    float* __restrict__ mats, float* __restrict__ depths)
{
    int tid = blockIdx.x * 256 + threadIdx.x;
    const int srcPad = SS * PN;             // 52800
    if (tid < srcPad) {
        int s = tid / PN;
        int rem = tid % PN;
        int py = rem / PW;
        int px = rem % PW;
        _Float16 v[CC] = {};                // zeros for border texels
        if (py >= 1 && py <= HH && px >= 2 && px <= WW + 1) {
            int p = (py - 1) * WW + (px - 2);
            const float* base = src + (size_t)s * CC * NN + p;
#pragma unroll
            for (int c = 0; c < CC; ++c) v[c] = (_Float16)base[c * NN];
        }
        H8* o = (H8*)(srcT + (size_t)tid * CC);
        o[0] = *(H8*)&v[0];
        o[1] = *(H8*)&v[8];
    } else if (tid < srcPad + NN) {
        int p = tid - srcPad;
        const float* base = cur + p;
        _Float16 v[CC];
#pragma unroll
        for (int c = 0; c < CC; ++c) v[c] = (_Float16)base[c * NN];
        H8* o = (H8*)(curT + (size_t)p * CC);
        o[0] = *(H8*)&v[0];
        o[1] = *(H8*)&v[8];
    }
    if (blockIdx.x == 0) {
        if (threadIdx.x < DD) {
            float lmn = logf(mnp[0]);
            float lr  = logf(mxp[0] / mnp[0]);
            depths[threadIdx.x] = expf(lmn + lr * ((float)threadIdx.x * (1.0f / (DD - 1))));
        } else if (threadIdx.x < DD + SS) {
            int s = threadIdx.x - DD;
            float P[3][4];
            for (int i = 0; i < 3; ++i)
                for (int j = 0; j < 4; ++j) {
                    float a = 0.f;
                    for (int k = 0; k < 4; ++k)
                        a += Ks[s * 16 + i * 4 + k] * ext[s * 16 + k * 4 + j];
                    P[i][j] = a;
                }
            for (int i = 0; i < 3; ++i) {
                for (int j = 0; j < 3; ++j) {
                    float a = 0.f;
                    for (int k = 0; k < 3; ++k)
                        a += P[i][k] * invK[k * 4 + j];
                    mats[s * 12 + i * 3 + j] = a;
                }
                mats[s * 12 + 9 + i] = P[i][3];
            }
        }
    }
}

// Main: block = 8x8 pixel tile x 4 consecutive depths (one depth per wave).
// Quad-cooperative taps: lane = 4*g + q; quad q loads the q-th 16B chunk of
// pixel g's contiguous 64B tap-pair (left tap 32B | right tap 32B). Each load
// instruction covers 16 px as contiguous 64B runs -> ~3x fewer distinct cache
// lines per instruction than the 1-px/lane layout. Partial dots are weighted
// in-lane; the quad-sum is deferred to 2 shfl_xor per accumulator at the end.
// No LDS, no barriers.
__global__ __launch_bounds__(256, 4) void cost_kernel(
    const _Float16* __restrict__ curT, const _Float16* __restrict__ srcT,
    const float* __restrict__ mats, const float* __restrict__ depths,
    float* __restrict__ out)
{
    int tid = threadIdx.x;
    const int TX = WW / 8;                 // 12
    const int TY = HH / 8;                 // 8
    int bx = blockIdx.x;
    int dg  = bx / (TX * TY);              // 0..15
    int rem = bx % (TX * TY);
    int tyi = rem / TX;
    int txi = rem % TX;
    int lane = tid & 63;
    int dsub = tid >> 6;                   // wave index = depth sub-index
    int d  = dg * 4 + dsub;

    int g = lane >> 2;                     // pixel group 0..15 (2 tile rows x 8 cols)
    int q = lane & 3;                      // 16B chunk within the 64B tap-pair
    int col  = g & 7;
    int rowp = g >> 3;                     // row parity within the iter pair
    int px = txi * 8 + col;

    float x  = (float)px + 0.5f;
    float y0 = (float)(tyi * 8 + rowp) + 0.5f;   // y of iter 0; +2 per iter

    // cur chunk (q&1) for each of this lane's 4 pixels (depth/source-invariant)
    H8 cur16[4];
#pragma unroll
    for (int i = 0; i < 4; ++i) {
        int n = (tyi * 8 + i * 2 + rowp) * WW + px;
        cur16[i] = *(const H8*)(curT + (size_t)n * CC + (q & 1) * 8);
    }

    // d is wave-uniform; force scalar load of the depth
    float depth = depths[__builtin_amdgcn_readfirstlane(d)];

    float acc[4] = {0.f, 0.f, 0.f, 0.f};

#pragma unroll 1
    for (int s = 0; s < SS; ++s) {
        const float* m = &mats[s * 12];    // s loop-uniform -> s_load
        float m0 = m[0], m1 = m[1], m2 = m[2], m3 = m[3], m4 = m[4], m5 = m[5];
        float m6 = m[6], m7 = m[7], m8 = m[8], m9 = m[9], m10 = m[10], m11 = m[11];
        float qx = m0 * x + m1 * y0 + m2;
        float qy = m3 * x + m4 * y0 + m5;
        float qz = m6 * x + m7 * y0 + m8;
        float uc[4], vc[4];
        bool any = false;
#pragma unroll
        for (int i = 0; i < 4; ++i) {
            float pz = depth * qz + m11;
            bool ok = pz > 0.f;
            float r = __builtin_amdgcn_rcpf(pz + 1e-8f);   // u = px/(z+EPS) per ref
            float u = (depth * qx + m9)  * r - 0.5f;
            float v = (depth * qy + m10) * r - 0.5f;
            any = any || (ok && (u > -1.f) && (u < (float)WW) && (v > -1.f) && (v < (float)HH));
            // float-side clamps keep both taps inside the padded image; !ok -> zero border
            uc[i] = ok ? fminf(fmaxf(u, -2.0f), 96.5f) : -2.0f;
            vc[i] = ok ? fminf(fmaxf(v, -1.0f), 64.5f) : -1.0f;
            qx += 2.f * m1; qy += 2.f * m4; qz += 2.f * m7;   // y += 2 per iter
        }
        if (__ballot(any) == 0ull) continue;   // whole (block,source) is exactly 0

        const _Float16* sb = srcT + (size_t)s * (PN * CC);
#pragma unroll
        for (int i = 0; i < 4; ++i) {
            float x0f = floorf(uc[i]), y0f = floorf(vc[i]);
            float wx = uc[i] - x0f, wy = vc[i] - y0f;
            int x0p = (int)x0f + 2;                  // [0, 98]
            int y0p = (int)y0f + 1;                  // [0, 65]
            int y1p = min(y0p + 1, PH - 1);          // [1, 65]
            const H8* t0 = (const H8*)(sb + (size_t)(y0p * PW + x0p) * CC) + q;
            const H8* t1 = (const H8*)(sb + (size_t)(y1p * PW + x0p) * CC) + q;
            H8 a = *t0, b = *t1;
            float p0 = 0.f, p1 = 0.f;
#pragma unroll
            for (int j = 0; j < 4; ++j) {
                p0 = __builtin_amdgcn_fdot2(a.v[j], cur16[i].v[j], p0, false);
                p1 = __builtin_amdgcn_fdot2(b.v[j], cur16[i].v[j], p1, false);
            }
            float t  = p0 + wy * (p1 - p0);          // row lerp
            float wq = (q < 2) ? (1.f - wx) : wx;    // left/right tap weight
            acc[i] += wq * t;
        }
    }

    // quad reduction: each acc[i] summed over the 4 chunk-lanes (masks 1,2 stay in-quad)
#pragma unroll
    for (int i = 0; i < 4; ++i) {
        acc[i] += __shfl_xor(acc[i], 1);
        acc[i] += __shfl_xor(acc[i], 2);
    }

    // lane l writes pixel (iter = l&3, group g = l>>2): static-index select
    float val = acc[0];
    val = (q == 1) ? acc[1] : val;
    val = (q == 2) ? acc[2] : val;
    val = (q == 3) ? acc[3] : val;
    int py_w = tyi * 8 + (lane & 3) * 2 + (lane >> 5);
    int px_w = txi * 8 + ((lane >> 2) & 7);
    int n_w  = py_w * WW + px_w;
    out[(size_t)d * NN + n_w] = val;                       // cost_volume
    out[(size_t)DD * NN + (size_t)d * NN + n_w] = depth;   // depth_planes
}

extern "C" void kernel_launch(void* const* d_in, const int* in_sizes, int n_in,
                              void* d_out, int out_size, void* d_ws, size_t ws_size,
                              hipStream_t stream) {
    const float* cur  = (const float*)d_in[0];
    const float* src  = (const float*)d_in[1];
    const float* ext  = (const float*)d_in[2];
    const float* Ks   = (const float*)d_in[3];
    const float* invK = (const float*)d_in[4];
    const float* mn   = (const float*)d_in[5];
    const float* mx   = (const float*)d_in[6];
    float* out = (float*)d_out;

    char* ws = (char*)d_ws;
    _Float16* srcT = (_Float16*)ws;                     // S*PN*C halfs ≈ 1.69 MB
    _Float16* curT = srcT + (size_t)SS * PN * CC;       // N*C halfs
    float* mats    = (float*)(curT + (size_t)NN * CC);  // 96
    float* depths  = mats + SS * 12;                    // 64

    int prepThreads = SS * PN + NN;                     // 58944
    int prepBlocks = (prepThreads + 255) / 256;         // 231
    prep_kernel<<<prepBlocks, 256, 0, stream>>>(cur, src, ext, Ks, invK, mn, mx,
                                                srcT, curT, mats, depths);
    cost_kernel<<<(DD / 4) * (WW / 8) * (HH / 8), 256, 0, stream>>>(curT, srcT, mats, depths, out);
}

// Round 4
// 82.935 us; speedup vs baseline: 1.1754x; 1.1036x over previous
//
#include <hip/hip_runtime.h>
#include <math.h>

#define SS 8
#define CC 16
#define HH 64
#define WW 96
#define DD 64
#define NN (HH*WW)
#define PW 100            // padded width: 2 zero cols each side
#define PH 66             // padded height: 1 zero row each side
#define PN (PH*PW)        // 6600 padded pixels per source

typedef _Float16 h2 __attribute__((ext_vector_type(2)));
struct alignas(16) H8 { h2 v[4]; };   // 8 halfs = 16 B

// Prep: transpose+convert src (S,C,H,W) -> f16 zero-padded channel-last
// (S, PH, PW, C); cur (C,H,W) -> f16 (H,W,C). Border texels written as zeros
// so OOB bilinear taps read 0 with no per-tap masking in the main kernel.
// Also folded projection matrices and the 64 log-spaced depths.
__global__ __launch_bounds__(256) void prep_kernel(
    const float* __restrict__ cur, const float* __restrict__ src,
    const float* __restrict__ ext, const float* __restrict__ Ks,
    const float* __restrict__ invK, const float* __restrict__ mnp,
    const float* __restrict__ mxp,
    _Float16* __restrict__ srcT, _Float16* __restrict__ curT,
    float* __restrict__ mats, float* __restrict__ depths)
{
    int tid = blockIdx.x * 256 + threadIdx.x;
    const int srcPad = SS * PN;             // 52800
    if (tid < srcPad) {
        int s = tid / PN;
        int rem = tid % PN;
        int py = rem / PW;
        int px = rem % PW;
        _Float16 v[CC] = {};                // zeros for border texels
        if (py >= 1 && py <= HH && px >= 2 && px <= WW + 1) {
            int p = (py - 1) * WW + (px - 2);
            const float* base = src + (size_t)s * CC * NN + p;
#pragma unroll
            for (int c = 0; c < CC; ++c) v[c] = (_Float16)base[c * NN];
        }
        H8* o = (H8*)(srcT + (size_t)tid * CC);
        o[0] = *(H8*)&v[0];
        o[1] = *(H8*)&v[8];
    } else if (tid < srcPad + NN) {
        int p = tid - srcPad;
        const float* base = cur + p;
        _Float16 v[CC];
#pragma unroll
        for (int c = 0; c < CC; ++c) v[c] = (_Float16)base[c * NN];
        H8* o = (H8*)(curT + (size_t)p * CC);
        o[0] = *(H8*)&v[0];
        o[1] = *(H8*)&v[8];
    }
    if (blockIdx.x == 0) {
        if (threadIdx.x < DD) {
            float lmn = logf(mnp[0]);
            float lr  = logf(mxp[0] / mnp[0]);
            depths[threadIdx.x] = expf(lmn + lr * ((float)threadIdx.x * (1.0f / (DD - 1))));
        } else if (threadIdx.x < DD + SS) {
            int s = threadIdx.x - DD;
            float P[3][4];
            for (int i = 0; i < 3; ++i)
                for (int j = 0; j < 4; ++j) {
                    float a = 0.f;
                    for (int k = 0; k < 4; ++k)
                        a += Ks[s * 16 + i * 4 + k] * ext[s * 16 + k * 4 + j];
                    P[i][j] = a;
                }
            for (int i = 0; i < 3; ++i) {
                for (int j = 0; j < 3; ++j) {
                    float a = 0.f;
                    for (int k = 0; k < 3; ++k)
                        a += P[i][k] * invK[k * 4 + j];
                    mats[s * 12 + i * 3 + j] = a;
                }
                mats[s * 12 + 9 + i] = P[i][3];
            }
        }
    }
}

// Main: identical math/instruction stream to the verified 82.7us kernel
// (1 pixel-depth per lane, 8 direct 16B gathers + 16 fdot2 per source,
// unroll 2, LB(256,6)). ONLY change: lane->(pixel,depth) remap. A wave now
// holds 16 pixels x 4 CONSECUTIVE depths (lane = dloc*16 + p16) instead of
// 64 pixels x 1 depth. Consecutive log-depths have sub-pixel disparity steps
// over most of the range, so the 4 depth-copies of each pixel gather the
// same or adjacent texel lines -> fewer distinct 64B lines per gather
// instruction and better within-wave L1 reuse, at unchanged occupancy, MLP,
// and VALU count.
__global__ __launch_bounds__(256, 6) void cost_kernel(
    const _Float16* __restrict__ curT, const _Float16* __restrict__ srcT,
    const float* __restrict__ mats, const float* __restrict__ depths,
    float* __restrict__ out)
{
    int tid = threadIdx.x;
    const int TX = WW / 8;                 // 12
    const int TY = HH / 8;                 // 8
    int bx = blockIdx.x;
    int dg  = bx / (TX * TY);              // 0..15
    int rem = bx % (TX * TY);
    int tyi = rem / TX;
    int txi = rem % TX;
    int lane = tid & 63;
    int w    = tid >> 6;                   // wave = row-pair of the 8x8 tile
    int dloc = lane >> 4;                  // 0..3: depth within the group
    int p16  = lane & 15;                  // 16 pixels per depth: 2 rows x 8 cols
    int r = p16 >> 3;
    int c = p16 & 7;
    int d  = dg * 4 + dloc;
    int px = txi * 8 + c;
    int py = tyi * 8 + w * 2 + r;
    int n  = py * WW + px;

    float x = (float)px + 0.5f;
    float y = (float)py + 0.5f;

    const H8* cp = (const H8*)(curT + (size_t)n * CC);
    H8 cA = cp[0], cB = cp[1];
    float depth = depths[d];               // per-lane (4 distinct values/wave)

    float acc = 0.f;
#pragma unroll 2
    for (int s = 0; s < SS; ++s) {
        const float* m = &mats[s * 12];    // s loop-uniform -> s_load
        float m0 = m[0], m1 = m[1], m2 = m[2], m3 = m[3], m4 = m[4], m5 = m[5];
        float m6 = m[6], m7 = m[7], m8 = m[8], m9 = m[9], m10 = m[10], m11 = m[11];
        float qx = m0 * x + m1 * y + m2;
        float qy = m3 * x + m4 * y + m5;
        float qz = m6 * x + m7 * y + m8;
        float pz = depth * qz + m11;
        bool ok = pz > 0.f;
        float rr = __builtin_amdgcn_rcpf(pz + 1e-8f);  // u = px/(z+EPS) per ref
        float u = (depth * qx + m9)  * rr - 0.5f;
        float v = (depth * qy + m10) * rr - 0.5f;
        // wave-uniform skip: contribution is exactly 0 when z<=0 or all 4 taps OOB
        bool contrib = ok && (u > -1.f) && (u < (float)WW) && (v > -1.f) && (v < (float)HH);
        if (__ballot(contrib) == 0ull) continue;
        // float-side clamps keep both taps of each pair inside the padded image
        // and in the zero border when OOB (v_med3_f32); !ok -> far border
        float uc = ok ? fminf(fmaxf(u, -2.0f), 96.5f) : -2.0f;
        float vc = ok ? fminf(fmaxf(v, -1.0f), 64.5f) : -1.0f;
        float x0f = floorf(uc), y0f = floorf(vc);
        float wx = uc - x0f, wy = vc - y0f;
        int x0p = (int)x0f + 2;                  // [0, 98]
        int y0p = (int)y0f + 1;                  // [0, 65]
        int y1p = min(y0p + 1, PH - 1);          // [1, 65]
        const _Float16* sbase = srcT + (size_t)s * (PN * CC);
        const H8* r0 = (const H8*)(sbase + (size_t)(y0p * PW + x0p) * CC);
        const H8* r1 = (const H8*)(sbase + (size_t)(y1p * PW + x0p) * CC);
        H8 a0 = r0[0], a1 = r0[1], a2 = r0[2], a3 = r0[3];   // row0: left|right tap
        H8 b0 = r1[0], b1 = r1[1], b2 = r1[2], b3 = r1[3];   // row1: left|right tap
        float dL0 = 0.f, dR0 = 0.f, dL1 = 0.f, dR1 = 0.f;
#pragma unroll
        for (int q = 0; q < 4; ++q) {
            dL0 = __builtin_amdgcn_fdot2(a0.v[q], cA.v[q], dL0, false);
            dL0 = __builtin_amdgcn_fdot2(a1.v[q], cB.v[q], dL0, false);
            dR0 = __builtin_amdgcn_fdot2(a2.v[q], cA.v[q], dR0, false);
            dR0 = __builtin_amdgcn_fdot2(a3.v[q], cB.v[q], dR0, false);
            dL1 = __builtin_amdgcn_fdot2(b0.v[q], cA.v[q], dL1, false);
            dL1 = __builtin_amdgcn_fdot2(b1.v[q], cB.v[q], dL1, false);
            dR1 = __builtin_amdgcn_fdot2(b2.v[q], cA.v[q], dR1, false);
            dR1 = __builtin_amdgcn_fdot2(b3.v[q], cB.v[q], dR1, false);
        }
        float d0 = dL0 + wx * (dR0 - dL0);
        float d1 = dL1 + wx * (dR1 - dL1);
        acc += d0 + wy * (d1 - d0);
    }
    out[(size_t)d * NN + n] = acc;                      // cost_volume
    out[(size_t)DD * NN + (size_t)d * NN + n] = depth;  // depth_planes
}

extern "C" void kernel_launch(void* const* d_in, const int* in_sizes, int n_in,
                              void* d_out, int out_size, void* d_ws, size_t ws_size,
                              hipStream_t stream) {
    const float* cur  = (const float*)d_in[0];
    const float* src  = (const float*)d_in[1];
    const float* ext  = (const float*)d_in[2];
    const float* Ks   = (const float*)d_in[3];
    const float* invK = (const float*)d_in[4];
    const float* mn   = (const float*)d_in[5];
    const float* mx   = (const float*)d_in[6];
    float* out = (float*)d_out;

    char* ws = (char*)d_ws;
    _Float16* srcT = (_Float16*)ws;                     // S*PN*C halfs ≈ 1.69 MB
    _Float16* curT = srcT + (size_t)SS * PN * CC;       // N*C halfs
    float* mats    = (float*)(curT + (size_t)NN * CC);  // 96
    float* depths  = mats + SS * 12;                    // 64

    int prepThreads = SS * PN + NN;                     // 58944
    int prepBlocks = (prepThreads + 255) / 256;         // 231
    prep_kernel<<<prepBlocks, 256, 0, stream>>>(cur, src, ext, Ks, invK, mn, mx,
                                                srcT, curT, mats, depths);
    cost_kernel<<<(DD / 4) * (WW / 8) * (HH / 8), 256, 0, stream>>>(curT, srcT, mats, depths, out);
}